// Round 9
// baseline (850.970 us; speedup 1.0000x reference)
//
#include <hip/hip_runtime.h>
#include <hip/hip_bf16.h>

using short8  = __attribute__((ext_vector_type(8))) short;
using float4v = __attribute__((ext_vector_type(4))) float;

__device__ __forceinline__ float4 f4zero() { return make_float4(0.f, 0.f, 0.f, 0.f); }

__device__ __forceinline__ void fma4(float4& a, float s, const float4& wv) {
    a.x = fmaf(s, wv.x, a.x);
    a.y = fmaf(s, wv.y, a.y);
    a.z = fmaf(s, wv.z, a.z);
    a.w = fmaf(s, wv.w, a.w);
}

__device__ __forceinline__ float bfhi2f(unsigned short u) {
    return __uint_as_float(((unsigned int)u) << 16);
}
__device__ __forceinline__ unsigned short f2bf_rn(float x) {
    unsigned int u = __float_as_uint(x);
    u += 0x7FFFu + ((u >> 16) & 1u);
    return (unsigned short)(u >> 16);
}
__device__ __forceinline__ void split_bf(float v, unsigned short& h, unsigned short& l) {
    h = f2bf_rn(v);
    l = f2bf_rn(v - bfhi2f(h));
}
__device__ __forceinline__ short8 ld_s8(const unsigned short* p) {   // 16B-aligned
    return *(const short8*)p;
}

// ---------------- weight prep: W[K][N] -> hi/lo bf16, transposed [N][Kpad] ----------------
__global__ __launch_bounds__(256) void tsplit_kernel(
    const float* __restrict__ W, int K, int N, int Kpad,
    unsigned short* __restrict__ oh, unsigned short* __restrict__ ol)
{
    const int idx = blockIdx.x * 256 + threadIdx.x;
    if (idx >= N * Kpad) return;
    const int n = idx / Kpad, k = idx - n * Kpad;
    const float v = (k < K) ? W[(size_t)k * N + n] : 0.f;
    unsigned short h, l;
    split_bf(v, h, l);
    oh[idx] = h; ol[idx] = l;
}

// ---------------- sort pipeline ----------------
__global__ __launch_bounds__(256) void hist_kernel(
    const int* __restrict__ ei, int* __restrict__ cnt, int E)
{
    const int i = blockIdx.x * blockDim.x + threadIdx.x;
    if (i < E) atomicAdd(&cnt[ei[E + i]], 1);
}

__global__ __launch_bounds__(256) void scan_kernel(
    const int* __restrict__ cnt, int* __restrict__ fill, int n)
{
    __shared__ int part[256];
    const int tid = threadIdx.x;
    const int chunk = (n + 255) / 256;
    const int beg = tid * chunk;
    const int end = min(beg + chunk, n);
    int s = 0;
    for (int i = beg; i < end; ++i) s += cnt[i];
    part[tid] = s;
    __syncthreads();
    for (int off = 1; off < 256; off <<= 1) {
        const int v = (tid >= off) ? part[tid - off] : 0;
        __syncthreads();
        part[tid] += v;
        __syncthreads();
    }
    int prefix = (tid == 0) ? 0 : part[tid - 1];
    for (int i = beg; i < end; ++i) { fill[i] = prefix; prefix += cnt[i]; }
}

__global__ __launch_bounds__(256) void scatter_kernel(
    const int* __restrict__ ei, int* __restrict__ fill,
    int* __restrict__ perm, int* __restrict__ ssrc, int* __restrict__ sdst, int E)
{
    const int e = blockIdx.x * blockDim.x + threadIdx.x;
    if (e < E) {
        const int d = ei[E + e];
        const int pos = atomicAdd(&fill[d], 1);
        perm[pos] = e;
        ssrc[pos] = ei[e];
        sdst[pos] = d;
    }
}

// ---------------- encode: h = relu(X[M,32] @ W[32,128] + b) ----------------
__global__ __launch_bounds__(256) void encode_nodes_kernel(
    const float* __restrict__ X, const float* __restrict__ W,
    const float* __restrict__ bias, float* __restrict__ out, int M)
{
    __shared__ float w[32 * 128];
    __shared__ float xs[2][32];
    const int tid = threadIdx.x;
    const int j = tid & 127;
    const int slot = tid >> 7;
    for (int idx = tid; idx < 32 * 128; idx += 256) w[idx] = W[idx];
    __syncthreads();
    const float bj = bias[j];
    for (int r0 = blockIdx.x * 2; r0 < M; r0 += gridDim.x * 2) {
        const int r = r0 + slot;
        const bool valid = r < M;
        if (valid && j < 32) xs[slot][j] = X[(size_t)r * 32 + j];
        __syncthreads();
        if (valid) {
            float a = bj;
#pragma unroll
            for (int k = 0; k < 32; ++k) a = fmaf(xs[slot][k], w[k * 128 + j], a);
            out[(size_t)r * 128 + j] = fmaxf(a, 0.f);
        }
        __syncthreads();
    }
}

// ---- C[M,128] = act( [A1 | A2][M,K] @ W[K,128] + bias ), K in {128,256} ----
__global__ __launch_bounds__(256) void sgemm_kernel(
    const float* __restrict__ A1, const float* __restrict__ A2,
    const float* __restrict__ W, const float* __restrict__ bias,
    float* __restrict__ C, int M, int K, int relu_flag)
{
    __shared__ float Xt[64 * 68];
    __shared__ float Ws[64 * 128];
    const int tid = threadIdx.x;
    const int tx = tid & 31;
    const int ty = tid >> 5;
    const int r0 = blockIdx.x * 64;

    float4 acc[8];
#pragma unroll
    for (int i = 0; i < 8; ++i) acc[i] = f4zero();

    for (int k0 = 0; k0 < K; k0 += 64) {
        const float* A = (k0 < 128) ? A1 : A2;
        const int kb = k0 & 127;
        __syncthreads();
#pragma unroll
        for (int rep = 0; rep < 4; ++rep) {
            const int fid = tid + rep * 256;
            const int row = fid >> 4, kq = fid & 15;
            float4 v = f4zero();
            const int r = r0 + row;
            if (r < M) v = *(const float4*)&A[(size_t)r * 128 + kb + 4 * kq];
            Xt[(4 * kq + 0) * 68 + row] = v.x;
            Xt[(4 * kq + 1) * 68 + row] = v.y;
            Xt[(4 * kq + 2) * 68 + row] = v.z;
            Xt[(4 * kq + 3) * 68 + row] = v.w;
        }
#pragma unroll
        for (int rep = 0; rep < 8; ++rep) {
            const int fid = tid + rep * 256;
            const int row = fid >> 5, cq = fid & 31;
            *(float4*)&Ws[row * 128 + 4 * cq] =
                *(const float4*)&W[(size_t)(k0 + row) * 128 + 4 * cq];
        }
        __syncthreads();
#pragma unroll 4
        for (int kk = 0; kk < 64; ++kk) {
            const float4 w4 = *(const float4*)&Ws[kk * 128 + 4 * tx];
            const float4 xa = *(const float4*)&Xt[kk * 68 + 8 * ty];
            const float4 xb = *(const float4*)&Xt[kk * 68 + 8 * ty + 4];
            fma4(acc[0], xa.x, w4); fma4(acc[1], xa.y, w4);
            fma4(acc[2], xa.z, w4); fma4(acc[3], xa.w, w4);
            fma4(acc[4], xb.x, w4); fma4(acc[5], xb.y, w4);
            fma4(acc[6], xb.z, w4); fma4(acc[7], xb.w, w4);
        }
    }
    float4 b4 = f4zero();
    if (bias) b4 = *(const float4*)&bias[4 * tx];
#pragma unroll
    for (int i = 0; i < 8; ++i) {
        const int r = r0 + 8 * ty + i;
        if (r < M) {
            float4 v;
            v.x = acc[i].x + b4.x; v.y = acc[i].y + b4.y;
            v.z = acc[i].z + b4.z; v.w = acc[i].w + b4.w;
            if (relu_flag) {
                v.x = fmaxf(v.x, 0.f); v.y = fmaxf(v.y, 0.f);
                v.z = fmaxf(v.z, 0.f); v.w = fmaxf(v.w, 0.f);
            }
            *(float4*)&C[(size_t)r * 128 + 4 * tx] = v;
        }
    }
}

// ---- C1 = A@W1, C2 = A@W2 (K=128, no bias/act) — fused paired projections ----
__global__ __launch_bounds__(256) void sgemm_dual_kernel(
    const float* __restrict__ A,
    const float* __restrict__ W1, const float* __restrict__ W2,
    float* __restrict__ C1, float* __restrict__ C2, int M)
{
    __shared__ float Xt[32 * 68];     // [k 32][row 64]
    __shared__ float Ws1[32 * 128];
    __shared__ float Ws2[32 * 128];
    const int tid = threadIdx.x;
    const int tx = tid & 31;
    const int ty = tid >> 5;
    const int r0 = blockIdx.x * 64;

    float4 a1[8], a2[8];
#pragma unroll
    for (int i = 0; i < 8; ++i) { a1[i] = f4zero(); a2[i] = f4zero(); }

    for (int k0 = 0; k0 < 128; k0 += 32) {
        __syncthreads();
#pragma unroll
        for (int rep = 0; rep < 2; ++rep) {
            const int fid = tid + rep * 256;
            const int row = fid >> 3, kq = fid & 7;
            float4 v = f4zero();
            const int r = r0 + row;
            if (r < M) v = *(const float4*)&A[(size_t)r * 128 + k0 + 4 * kq];
            Xt[(4 * kq + 0) * 68 + row] = v.x;
            Xt[(4 * kq + 1) * 68 + row] = v.y;
            Xt[(4 * kq + 2) * 68 + row] = v.z;
            Xt[(4 * kq + 3) * 68 + row] = v.w;
        }
#pragma unroll
        for (int rep = 0; rep < 4; ++rep) {
            const int fid = tid + rep * 256;
            const int row = fid >> 5, cq = fid & 31;
            *(float4*)&Ws1[row * 128 + 4 * cq] =
                *(const float4*)&W1[(size_t)(k0 + row) * 128 + 4 * cq];
            *(float4*)&Ws2[row * 128 + 4 * cq] =
                *(const float4*)&W2[(size_t)(k0 + row) * 128 + 4 * cq];
        }
        __syncthreads();
#pragma unroll 4
        for (int kk = 0; kk < 32; ++kk) {
            const float4 w1 = *(const float4*)&Ws1[kk * 128 + 4 * tx];
            const float4 w2 = *(const float4*)&Ws2[kk * 128 + 4 * tx];
            const float4 xa = *(const float4*)&Xt[kk * 68 + 8 * ty];
            const float4 xb = *(const float4*)&Xt[kk * 68 + 8 * ty + 4];
            fma4(a1[0], xa.x, w1); fma4(a1[1], xa.y, w1);
            fma4(a1[2], xa.z, w1); fma4(a1[3], xa.w, w1);
            fma4(a1[4], xb.x, w1); fma4(a1[5], xb.y, w1);
            fma4(a1[6], xb.z, w1); fma4(a1[7], xb.w, w1);
            fma4(a2[0], xa.x, w2); fma4(a2[1], xa.y, w2);
            fma4(a2[2], xa.z, w2); fma4(a2[3], xa.w, w2);
            fma4(a2[4], xb.x, w2); fma4(a2[5], xb.y, w2);
            fma4(a2[6], xb.z, w2); fma4(a2[7], xb.w, w2);
        }
    }
#pragma unroll
    for (int i = 0; i < 8; ++i) {
        const int r = r0 + 8 * ty + i;
        if (r < M) {
            *(float4*)&C1[(size_t)r * 128 + 4 * tx] = a1[i];
            *(float4*)&C2[(size_t)r * 128 + 4 * tx] = a2[i];
        }
    }
}

// ---- fused edge path: 32-edge tiles, 128 threads, split-bf16 MFMA ----
// Wave w covers cols 64w..64w+63 (4 n-tiles); 2 m-tiles of 16 edges.
__global__ __launch_bounds__(128, 4) void edge_msg_mfma_kernel(
    const float* __restrict__ edge_feats,
    const int* __restrict__ perm, const int* __restrict__ ssrc, const int* __restrict__ sdst,
    const unsigned short* __restrict__ wehT_h, const unsigned short* __restrict__ wehT_l,
    const float* __restrict__ be,
    const unsigned short* __restrict__ wmT_h, const unsigned short* __restrict__ wmT_l,
    const float* __restrict__ bm,
    const float* __restrict__ Psrc, const float* __restrict__ Pdst,
    float* __restrict__ agg, int E)
{
    // LDS (bytes):
    //     0: ahi [32][136] u16 (8704)
    //  8704: alo [32][136] u16 (8704)
    // 17408: efh [32][40]  u16 (2560)
    // 19968: efl [32][40]  u16 (2560)
    // 22528: sdh[32] | 22656: ssh[32]  -> 22784 total (7 blocks/CU)
    // ms [32][132] f32 (16896) overlays ahi/alo after mid GEMM.
    __shared__ __align__(16) char smem[22784];
    unsigned short* ahi = (unsigned short*)smem;
    unsigned short* alo = (unsigned short*)(smem + 8704);
    unsigned short* efh = (unsigned short*)(smem + 17408);
    unsigned short* efl = (unsigned short*)(smem + 19968);
    int* sdh = (int*)(smem + 22528);
    int* ssh = (int*)(smem + 22656);
    float* ms = (float*)smem;

    const int tid = threadIdx.x;      // 0..127
    const int w = tid >> 6;           // wave 0..1
    const int l = tid & 63;
    const int quad = l >> 4;
    const int l16 = l & 15;
    const int p0 = blockIdx.x * 32;

    if (tid < 32) {
        const int p = p0 + tid;
        sdh[tid] = (p < E) ? sdst[p] : -1;
        ssh[tid] = (p < E) ? ssrc[p] : 0;
    }
    // zero ef pad k=16..31 and stage edge feats (row = tid>>2, 32 rows)
    {
        const int row = tid >> 2, fq = tid & 3;
        const int k16 = 16 + fq * 4;
        *(ulong1*)&efh[row * 40 + k16] = ulong1{0};
        *(ulong1*)&efl[row * 40 + k16] = ulong1{0};
        const int p = p0 + row;
        float4 v = f4zero();
        if (p < E) {
            const int e = perm[p];
            v = *(const float4*)&edge_feats[(size_t)e * 16 + 4 * fq];
        }
        unsigned short h, lo;
        split_bf(v.x, h, lo); efh[row * 40 + 4 * fq + 0] = h; efl[row * 40 + 4 * fq + 0] = lo;
        split_bf(v.y, h, lo); efh[row * 40 + 4 * fq + 1] = h; efl[row * 40 + 4 * fq + 1] = lo;
        split_bf(v.z, h, lo); efh[row * 40 + 4 * fq + 2] = h; efl[row * 40 + 4 * fq + 2] = lo;
        split_bf(v.w, h, lo); efh[row * 40 + 4 * fq + 3] = h; efl[row * 40 + 4 * fq + 3] = lo;
    }
    __syncthreads();

    float4v acc[2][4];
#pragma unroll
    for (int mt = 0; mt < 2; ++mt)
#pragma unroll
        for (int t = 0; t < 4; ++t) acc[mt][t] = (float4v)0.f;

    // ---- he phase: MFMA over K=32 (zero-padded) ----
    {
        short8 bh[4], bl[4];
#pragma unroll
        for (int t = 0; t < 4; ++t) {
            const int g = ((4 * w + t) * 16 + l16) * 32 + quad * 8;
            bh[t] = ld_s8(&wehT_h[g]);
            bl[t] = ld_s8(&wehT_l[g]);
        }
#pragma unroll
        for (int mt = 0; mt < 2; ++mt) {
            const int base = (mt * 16 + l16) * 40 + quad * 8;
            const short8 ah = ld_s8(&efh[base]);
            const short8 al = ld_s8(&efl[base]);
#pragma unroll
            for (int t = 0; t < 4; ++t) {
                acc[mt][t] = __builtin_amdgcn_mfma_f32_16x16x32_bf16(ah, bh[t], acc[mt][t], 0, 0, 0);
                acc[mt][t] = __builtin_amdgcn_mfma_f32_16x16x32_bf16(ah, bl[t], acc[mt][t], 0, 0, 0);
                acc[mt][t] = __builtin_amdgcn_mfma_f32_16x16x32_bf16(al, bh[t], acc[mt][t], 0, 0, 0);
            }
        }
        // bias + relu + split -> ahi/alo
#pragma unroll
        for (int t = 0; t < 4; ++t) {
            const int col = (4 * w + t) * 16 + l16;
            const float bcol = be[col];
#pragma unroll
            for (int mt = 0; mt < 2; ++mt)
#pragma unroll
                for (int r = 0; r < 4; ++r) {
                    const int row = mt * 16 + quad * 4 + r;
                    const float v = fmaxf(acc[mt][t][r] + bcol, 0.f);
                    unsigned short h, lo;
                    split_bf(v, h, lo);
                    ahi[row * 136 + col] = h;
                    alo[row * 136 + col] = lo;
                }
        }
    }
    __syncthreads();

    // ---- mid GEMM: K=128 in 4 chunks of 32; B direct from global ----
#pragma unroll
    for (int mt = 0; mt < 2; ++mt)
#pragma unroll
        for (int t = 0; t < 4; ++t) acc[mt][t] = (float4v)0.f;

#pragma unroll
    for (int c = 0; c < 4; ++c) {
        const int k0 = c * 32;
        short8 bh[4], bl[4];
#pragma unroll
        for (int t = 0; t < 4; ++t) {
            const int g = ((4 * w + t) * 16 + l16) * 128 + k0 + quad * 8;
            bh[t] = ld_s8(&wmT_h[g]);
            bl[t] = ld_s8(&wmT_l[g]);
        }
#pragma unroll
        for (int mt = 0; mt < 2; ++mt) {
            const int base = (mt * 16 + l16) * 136 + k0 + quad * 8;
            const short8 ah = ld_s8(&ahi[base]);
            const short8 al = ld_s8(&alo[base]);
#pragma unroll
            for (int t = 0; t < 4; ++t) {
                acc[mt][t] = __builtin_amdgcn_mfma_f32_16x16x32_bf16(ah, bh[t], acc[mt][t], 0, 0, 0);
                acc[mt][t] = __builtin_amdgcn_mfma_f32_16x16x32_bf16(ah, bl[t], acc[mt][t], 0, 0, 0);
                acc[mt][t] = __builtin_amdgcn_mfma_f32_16x16x32_bf16(al, bh[t], acc[mt][t], 0, 0, 0);
            }
        }
    }
    __syncthreads();   // ahi/alo reads done; safe to overlay ms

    // ---- spill mid to ms[32][132] ----
#pragma unroll
    for (int mt = 0; mt < 2; ++mt)
#pragma unroll
        for (int t = 0; t < 4; ++t) {
            const int col = (4 * w + t) * 16 + l16;
#pragma unroll
            for (int r = 0; r < 4; ++r)
                ms[(mt * 16 + quad * 4 + r) * 132 + col] = acc[mt][t][r];
        }
    __syncthreads();

    // ---- epilogue: + bm + Ps[src] + Pd[dst], relu (rows 8ty+i, ty=tid>>5 in 0..3) ----
    {
        const int tx = tid & 31, ty = tid >> 5;
        const float4 bm4 = *(const float4*)&bm[4 * tx];
#pragma unroll
        for (int i = 0; i < 8; ++i) {
            const int row = 8 * ty + i;
            const int p = p0 + row;
            if (p < E) {
                const int s = ssh[row];
                const int d = sdh[row];
                const float4 ps = *(const float4*)&Psrc[(size_t)s * 128 + 4 * tx];
                const float4 pd = *(const float4*)&Pdst[(size_t)d * 128 + 4 * tx];
                float4 m4 = *(const float4*)&ms[row * 132 + 4 * tx];
                m4.x = fmaxf(m4.x + bm4.x + ps.x + pd.x, 0.f);
                m4.y = fmaxf(m4.y + bm4.y + ps.y + pd.y, 0.f);
                m4.z = fmaxf(m4.z + bm4.z + ps.z + pd.z, 0.f);
                m4.w = fmaxf(m4.w + bm4.w + ps.w + pd.w, 0.f);
                *(float4*)&ms[row * 132 + 4 * tx] = m4;
            }
        }
    }
    __syncthreads();

    // ---- run-length segmented reduction: thread j scans all 32 rows of col j ----
    {
        const int j = tid;   // 0..127
        float a = 0.f;
        for (int r = 0; r < 32; ++r) {
            const int d = sdh[r];
            if (d < 0) break;
            a += ms[r * 132 + j];
            if (r == 31 || sdh[r + 1] != d) {
                atomicAdd(&agg[(size_t)d * 128 + j], a);
                a = 0.f;
            }
        }
    }
}

// ---- readout: one demand per wave, no in-loop barriers ----
__global__ __launch_bounds__(256) void readout_kernel(
    const float* __restrict__ Qs, const float* __restrict__ Qd,
    const float* __restrict__ df, const int* __restrict__ dp,
    const float* __restrict__ Wd, const float* __restrict__ b1,
    const float* __restrict__ w2, const float* __restrict__ b2,
    float* __restrict__ out, int D)
{
    __shared__ float wd[8 * 128];
    const int tid = threadIdx.x;
    const int wv = tid >> 6;
    const int l = tid & 63;
    for (int idx = tid; idx < 8 * 128; idx += 256) wd[idx] = Wd[idx];
    __syncthreads();
    const float b1a = b1[l], b1b = b1[l + 64];
    const float w2a = w2[l], w2b = w2[l + 64];
    const float bb = b2[0];
    for (int d = blockIdx.x * 4 + wv; d < D; d += gridDim.x * 4) {
        const int s = dp[2 * d], t = dp[2 * d + 1];
        float a = b1a + Qs[(size_t)s * 128 + l] + Qd[(size_t)t * 128 + l];
        float b = b1b + Qs[(size_t)s * 128 + l + 64] + Qd[(size_t)t * 128 + l + 64];
#pragma unroll
        for (int k = 0; k < 8; ++k) {
            const float f = df[(size_t)d * 8 + k];
            a = fmaf(f, wd[k * 128 + l], a);
            b = fmaf(f, wd[k * 128 + l + 64], b);
        }
        float v = fmaxf(a, 0.f) * w2a + fmaxf(b, 0.f) * w2b;
        for (int o = 32; o > 0; o >>= 1) v += __shfl_down(v, o);
        if (l == 0) out[d] = 1.f / (1.f + __expf(-(v + bb)));
    }
}

extern "C" void kernel_launch(void* const* d_in, const int* in_sizes, int n_in,
                              void* d_out, int out_size, void* d_ws, size_t ws_size,
                              hipStream_t stream)
{
    const float* node_feats   = (const float*)d_in[0];
    const float* edge_feats   = (const float*)d_in[1];
    const float* demand_feats = (const float*)d_in[2];
    const int*   ei = (const int*)d_in[3];
    const int*   dp = (const int*)d_in[4];
    const float* W_node = (const float*)d_in[5];
    const float* b_node = (const float*)d_in[6];
    const float* W_edge = (const float*)d_in[7];
    const float* b_edge = (const float*)d_in[8];
    const float* Wm[2] = {(const float*)d_in[9],  (const float*)d_in[13]};
    const float* bm[2] = {(const float*)d_in[10], (const float*)d_in[14]};
    const float* Wu[2] = {(const float*)d_in[11], (const float*)d_in[15]};
    const float* bu[2] = {(const float*)d_in[12], (const float*)d_in[16]};
    const float* W_r1 = (const float*)d_in[17];
    const float* b_r1 = (const float*)d_in[18];
    const float* W_r2 = (const float*)d_in[19];
    const float* b_r2 = (const float*)d_in[20];
    float* out = (float*)d_out;

    const int NN = in_sizes[0] / 32;   // 20000
    const int NE = in_sizes[3] / 2;    // 640000
    const int ND = in_sizes[4] / 2;    // 100000

    float* B0 = (float*)d_ws;
    float* B1 = B0 + (size_t)NN * 128;
    float* B2 = B1 + (size_t)NN * 128;
    float* B3 = B2 + (size_t)NN * 128;
    int* cnt  = (int*)(B3 + (size_t)NN * 128);
    int* fill = cnt + NN;
    int* perm = fill + NN;
    int* ssrc = perm + NE;
    int* sdst = ssrc + NE;
    unsigned short* wehT_h = (unsigned short*)(sdst + NE);
    unsigned short* wehT_l = wehT_h + 128 * 32;
    unsigned short* wm0_h  = wehT_l + 128 * 32;
    unsigned short* wm0_l  = wm0_h + 128 * 128;
    unsigned short* wm1_h  = wm0_l + 128 * 128;
    unsigned short* wm1_l  = wm1_h + 128 * 128;

    const int nbN = (NN + 63) / 64;
    const int nbE = (NE + 31) / 32;   // 32-edge tiles

    // ---- weight prep ----
    tsplit_kernel<<<16, 256, 0, stream>>>(W_edge, 16, 128, 32, wehT_h, wehT_l);
    tsplit_kernel<<<64, 256, 0, stream>>>(Wm[0] + 128 * 128, 128, 128, 128, wm0_h, wm0_l);
    tsplit_kernel<<<64, 256, 0, stream>>>(Wm[1] + 128 * 128, 128, 128, 128, wm1_h, wm1_l);

    // ---- sort edges by dst ----
    hipMemsetAsync(cnt, 0, NN * sizeof(int), stream);
    hist_kernel<<<(NE + 255) / 256, 256, 0, stream>>>(ei, cnt, NE);
    scan_kernel<<<1, 256, 0, stream>>>(cnt, fill, NN);
    scatter_kernel<<<(NE + 255) / 256, 256, 0, stream>>>(ei, fill, perm, ssrc, sdst, NE);

    encode_nodes_kernel<<<512, 256, 0, stream>>>(node_feats, W_node, b_node, B0, NN);

    // ---- layer 0: hin=B0 ----
    sgemm_dual_kernel<<<nbN, 256, 0, stream>>>(B0, Wm[0], Wm[0] + 256 * 128, B1, B2, NN);
    hipMemsetAsync(B3, 0, (size_t)NN * 128 * sizeof(float), stream);
    edge_msg_mfma_kernel<<<nbE, 128, 0, stream>>>(edge_feats, perm, ssrc, sdst,
                                                  wehT_h, wehT_l, b_edge,
                                                  wm0_h, wm0_l, bm[0], B1, B2, B3, NE);
    sgemm_kernel<<<nbN, 256, 0, stream>>>(B0, B3, Wu[0], bu[0], B1, NN, 256, 1);

    // ---- layer 1: hin=B1 ----
    sgemm_dual_kernel<<<nbN, 256, 0, stream>>>(B1, Wm[1], Wm[1] + 256 * 128, B0, B2, NN);
    hipMemsetAsync(B3, 0, (size_t)NN * 128 * sizeof(float), stream);
    edge_msg_mfma_kernel<<<nbE, 128, 0, stream>>>(edge_feats, perm, ssrc, sdst,
                                                  wehT_h, wehT_l, b_edge,
                                                  wm1_h, wm1_l, bm[1], B0, B2, B3, NE);
    sgemm_kernel<<<nbN, 256, 0, stream>>>(B1, B3, Wu[1], bu[1], B2, NN, 256, 1);

    // ---- readout ----
    sgemm_dual_kernel<<<nbN, 256, 0, stream>>>(B2, W_r1, W_r1 + 128 * 128, B0, B1, NN);
    readout_kernel<<<2048, 256, 0, stream>>>(B0, B1, demand_feats, dp,
                                             W_r1 + 256 * 128, b_r1, W_r2, b_r2, out, ND);
}

// Round 10
// 687.167 us; speedup vs baseline: 1.2384x; 1.2384x over previous
//
#include <hip/hip_runtime.h>
#include <hip/hip_bf16.h>

using short8  = __attribute__((ext_vector_type(8))) short;
using float4v = __attribute__((ext_vector_type(4))) float;

__device__ __forceinline__ float4 f4zero() { return make_float4(0.f, 0.f, 0.f, 0.f); }

__device__ __forceinline__ float bfhi2f(unsigned short u) {
    return __uint_as_float(((unsigned int)u) << 16);
}
__device__ __forceinline__ unsigned short f2bf_rn(float x) {
    unsigned int u = __float_as_uint(x);
    u += 0x7FFFu + ((u >> 16) & 1u);
    return (unsigned short)(u >> 16);
}
__device__ __forceinline__ void split_bf(float v, unsigned short& h, unsigned short& l) {
    h = f2bf_rn(v);
    l = f2bf_rn(v - bfhi2f(h));
}
__device__ __forceinline__ short8 ld_s8(const unsigned short* p) {   // 16B-aligned
    return *(const short8*)p;
}

// ---------------- weight prep ----------------
// generic: W[K][N] -> hi/lo bf16 transposed [N][Kpad], zero-padded
__global__ __launch_bounds__(256) void tsplit_kernel(
    const float* __restrict__ W, int K, int N, int Kpad,
    unsigned short* __restrict__ oh, unsigned short* __restrict__ ol)
{
    const int idx = blockIdx.x * 256 + threadIdx.x;
    if (idx >= N * Kpad) return;
    const int n = idx / Kpad, k = idx - n * Kpad;
    const float v = (k < K) ? W[(size_t)k * N + n] : 0.f;
    unsigned short h, l;
    split_bf(v, h, l);
    oh[idx] = h; ol[idx] = l;
}

struct SrcList8 { const float* p[8]; };
// eight K=128,N=128 matrices -> [n][128] each, packed at m*16384
__global__ __launch_bounds__(256) void tsplit8_kernel(
    SrcList8 src, unsigned short* __restrict__ dh, unsigned short* __restrict__ dl)
{
    const int m = blockIdx.x >> 6;                       // 64 blocks per matrix
    const int idx = (blockIdx.x & 63) * 256 + threadIdx.x;  // 0..16383
    const int n = idx >> 7, k = idx & 127;
    const float v = src.p[m][(size_t)k * 128 + n];
    unsigned short h, l;
    split_bf(v, h, l);
    dh[m * 16384 + idx] = h; dl[m * 16384 + idx] = l;
}

struct SrcList2 { const float* p[2]; };
// two K=256,N=128 matrices -> [n][256] each, packed at m*32768
__global__ __launch_bounds__(256) void tsplit2_kernel(
    SrcList2 src, unsigned short* __restrict__ dh, unsigned short* __restrict__ dl)
{
    const int m = blockIdx.x >> 7;                       // 128 blocks per matrix
    const int idx = (blockIdx.x & 127) * 256 + threadIdx.x; // 0..32767
    const int n = idx >> 8, k = idx & 255;
    const float v = src.p[m][(size_t)k * 128 + n];
    unsigned short h, l;
    split_bf(v, h, l);
    dh[m * 32768 + idx] = h; dl[m * 32768 + idx] = l;
}

// ---------------- sort pipeline ----------------
__global__ __launch_bounds__(256) void hist_kernel(
    const int* __restrict__ ei, int* __restrict__ cnt, int E)
{
    const int i = blockIdx.x * blockDim.x + threadIdx.x;
    if (i < E) atomicAdd(&cnt[ei[E + i]], 1);
}

__global__ __launch_bounds__(256) void scan_kernel(
    const int* __restrict__ cnt, int* __restrict__ fill, int n)
{
    __shared__ int part[256];
    const int tid = threadIdx.x;
    const int chunk = (n + 255) / 256;
    const int beg = tid * chunk;
    const int end = min(beg + chunk, n);
    int s = 0;
    for (int i = beg; i < end; ++i) s += cnt[i];
    part[tid] = s;
    __syncthreads();
    for (int off = 1; off < 256; off <<= 1) {
        const int v = (tid >= off) ? part[tid - off] : 0;
        __syncthreads();
        part[tid] += v;
        __syncthreads();
    }
    int prefix = (tid == 0) ? 0 : part[tid - 1];
    for (int i = beg; i < end; ++i) { fill[i] = prefix; prefix += cnt[i]; }
}

__global__ __launch_bounds__(256) void scatter_kernel(
    const int* __restrict__ ei, int* __restrict__ fill,
    int* __restrict__ perm, int* __restrict__ ssrc, int* __restrict__ sdst, int E)
{
    const int e = blockIdx.x * blockDim.x + threadIdx.x;
    if (e < E) {
        const int d = ei[E + e];
        const int pos = atomicAdd(&fill[d], 1);
        perm[pos] = e;
        ssrc[pos] = ei[e];
        sdst[pos] = d;
    }
}

// =====================================================================
// Fused node kernels (split-bf16 MFMA). Block = 64 rows x 128 cols,
// 256 threads / 4 waves; wave w covers n-tiles {2w,2w+1}; m-tiles 0..3.
// C = relu(A@W + b); then P1 = C@V1, P2 = C@V2 (K=128 projections).
// Weights pre-split transposed [n][k] in global.
// =====================================================================

// shared epilogue+projection body assumes: acc holds main GEMM result,
// ahi/alo free for reuse after a barrier.
__device__ __forceinline__ void node_epilogue_proj(
    float4v (&acc)[4][2], unsigned short* ahi, unsigned short* alo,
    const float* bias, const unsigned short* v1h, const unsigned short* v1l,
    const unsigned short* v2h, const unsigned short* v2l,
    float* C, float* P1, float* P2,
    int r0, int M, int w, int quad, int l16)
{
    __syncthreads();   // all A-frag reads of the main GEMM are done
    // C = relu(acc + bias); write C; split -> ahi/alo ([row][k] stride 136)
#pragma unroll
    for (int t = 0; t < 2; ++t) {
        const int col = (2 * w + t) * 16 + l16;
        const float bcol = bias[col];
#pragma unroll
        for (int mt = 0; mt < 4; ++mt)
#pragma unroll
            for (int r = 0; r < 4; ++r) {
                const int row = mt * 16 + quad * 4 + r;
                const float c = fmaxf(acc[mt][t][r] + bcol, 0.f);
                if (r0 + row < M) C[(size_t)(r0 + row) * 128 + col] = c;
                unsigned short h, l;
                split_bf(c, h, l);
                ahi[row * 136 + col] = h;
                alo[row * 136 + col] = l;
            }
    }
    __syncthreads();
    // projections: P = C @ V, K=128, B-frags direct from global
    const unsigned short* vh[2] = {v1h, v2h};
    const unsigned short* vl[2] = {v1l, v2l};
    float* P[2] = {P1, P2};
#pragma unroll
    for (int p = 0; p < 2; ++p) {
#pragma unroll
        for (int mt = 0; mt < 4; ++mt)
#pragma unroll
            for (int t = 0; t < 2; ++t) acc[mt][t] = (float4v)0.f;
#pragma unroll
        for (int c4 = 0; c4 < 4; ++c4) {
            const int k0 = c4 * 32;
            short8 bh[2], bl[2];
#pragma unroll
            for (int t = 0; t < 2; ++t) {
                const int g = ((2 * w + t) * 16 + l16) * 128 + k0 + quad * 8;
                bh[t] = ld_s8(&vh[p][g]);
                bl[t] = ld_s8(&vl[p][g]);
            }
#pragma unroll
            for (int mt = 0; mt < 4; ++mt) {
                const int base = (mt * 16 + l16) * 136 + k0 + quad * 8;
                const short8 ah = ld_s8(&ahi[base]);
                const short8 al = ld_s8(&alo[base]);
#pragma unroll
                for (int t = 0; t < 2; ++t) {
                    acc[mt][t] = __builtin_amdgcn_mfma_f32_16x16x32_bf16(ah, bh[t], acc[mt][t], 0, 0, 0);
                    acc[mt][t] = __builtin_amdgcn_mfma_f32_16x16x32_bf16(ah, bl[t], acc[mt][t], 0, 0, 0);
                    acc[mt][t] = __builtin_amdgcn_mfma_f32_16x16x32_bf16(al, bh[t], acc[mt][t], 0, 0, 0);
                }
            }
        }
        // scattered dword stores of P
#pragma unroll
        for (int t = 0; t < 2; ++t) {
            const int col = (2 * w + t) * 16 + l16;
#pragma unroll
            for (int mt = 0; mt < 4; ++mt)
#pragma unroll
                for (int r = 0; r < 4; ++r) {
                    const int row = mt * 16 + quad * 4 + r;
                    if (r0 + row < M) P[p][(size_t)(r0 + row) * 128 + col] = acc[mt][t][r];
                }
        }
    }
}

// encode: C = relu(X[M,32] @ Wn + b), then projections.
__global__ __launch_bounds__(256) void encode_mfma_kernel(
    const float* __restrict__ X,
    const unsigned short* __restrict__ wTh, const unsigned short* __restrict__ wTl, // [128][32]
    const float* __restrict__ bias,
    const unsigned short* __restrict__ v1h, const unsigned short* __restrict__ v1l,
    const unsigned short* __restrict__ v2h, const unsigned short* __restrict__ v2l,
    float* __restrict__ C, float* __restrict__ P1, float* __restrict__ P2, int M)
{
    __shared__ __align__(16) char smem[34816];
    unsigned short* ahi = (unsigned short*)smem;
    unsigned short* alo = (unsigned short*)(smem + 17408);
    const int tid = threadIdx.x;
    const int w = tid >> 6, l = tid & 63, quad = l >> 4, l16 = l & 15;
    const int r0 = blockIdx.x * 64;

    // stage X (64 x 32 fp32) split -> ahi/alo stride 136 (k in 0..31)
#pragma unroll
    for (int rep = 0; rep < 2; ++rep) {
        const int fid = tid + rep * 256;
        const int row = fid >> 3, kq = fid & 7;
        float4 v = f4zero();
        if (r0 + row < M) v = *(const float4*)&X[(size_t)(r0 + row) * 32 + 4 * kq];
        unsigned short h0, l0, h1, l1, h2, l2, h3, l3;
        split_bf(v.x, h0, l0); split_bf(v.y, h1, l1);
        split_bf(v.z, h2, l2); split_bf(v.w, h3, l3);
        uint2 hp; hp.x = (unsigned)h0 | ((unsigned)h1 << 16); hp.y = (unsigned)h2 | ((unsigned)h3 << 16);
        uint2 lp; lp.x = (unsigned)l0 | ((unsigned)l1 << 16); lp.y = (unsigned)l2 | ((unsigned)l3 << 16);
        *(uint2*)&ahi[row * 136 + 4 * kq] = hp;
        *(uint2*)&alo[row * 136 + 4 * kq] = lp;
    }
    __syncthreads();

    float4v acc[4][2];
#pragma unroll
    for (int mt = 0; mt < 4; ++mt)
#pragma unroll
        for (int t = 0; t < 2; ++t) acc[mt][t] = (float4v)0.f;

    {   // single K=32 chunk
        short8 bh[2], bl[2];
#pragma unroll
        for (int t = 0; t < 2; ++t) {
            const int g = ((2 * w + t) * 16 + l16) * 32 + quad * 8;
            bh[t] = ld_s8(&wTh[g]);
            bl[t] = ld_s8(&wTl[g]);
        }
#pragma unroll
        for (int mt = 0; mt < 4; ++mt) {
            const int base = (mt * 16 + l16) * 136 + quad * 8;
            const short8 ah = ld_s8(&ahi[base]);
            const short8 al = ld_s8(&alo[base]);
#pragma unroll
            for (int t = 0; t < 2; ++t) {
                acc[mt][t] = __builtin_amdgcn_mfma_f32_16x16x32_bf16(ah, bh[t], acc[mt][t], 0, 0, 0);
                acc[mt][t] = __builtin_amdgcn_mfma_f32_16x16x32_bf16(ah, bl[t], acc[mt][t], 0, 0, 0);
                acc[mt][t] = __builtin_amdgcn_mfma_f32_16x16x32_bf16(al, bh[t], acc[mt][t], 0, 0, 0);
            }
        }
    }
    node_epilogue_proj(acc, ahi, alo, bias, v1h, v1l, v2h, v2l, C, P1, P2, r0, M, w, quad, l16);
}

// update: C = relu([A1|A2][M,256] @ Wu + b), then projections.
__global__ __launch_bounds__(256) void update_mfma_kernel(
    const float* __restrict__ A1, const float* __restrict__ A2,
    const unsigned short* __restrict__ wTh, const unsigned short* __restrict__ wTl, // [128][256]
    const float* __restrict__ bias,
    const unsigned short* __restrict__ v1h, const unsigned short* __restrict__ v1l,
    const unsigned short* __restrict__ v2h, const unsigned short* __restrict__ v2l,
    float* __restrict__ C, float* __restrict__ P1, float* __restrict__ P2, int M)
{
    __shared__ __align__(16) char smem[34816];
    unsigned short* ahi = (unsigned short*)smem;
    unsigned short* alo = (unsigned short*)(smem + 17408);
    const int tid = threadIdx.x;
    const int w = tid >> 6, l = tid & 63, quad = l >> 4, l16 = l & 15;
    const int r0 = blockIdx.x * 64;

    float4v acc[4][2];
#pragma unroll
    for (int mt = 0; mt < 4; ++mt)
#pragma unroll
        for (int t = 0; t < 2; ++t) acc[mt][t] = (float4v)0.f;

    for (int half = 0; half < 2; ++half) {
        const float* A = half ? A2 : A1;
        if (half) __syncthreads();   // protect prior ahi reads before restage
        // stage 64 x 128 fp32 -> split
#pragma unroll
        for (int rep = 0; rep < 8; ++rep) {
            const int fid = tid + rep * 256;
            const int row = fid >> 5, kq = fid & 31;
            float4 v = f4zero();
            if (r0 + row < M) v = *(const float4*)&A[(size_t)(r0 + row) * 128 + 4 * kq];
            unsigned short h0, l0, h1, l1, h2, l2, h3, l3;
            split_bf(v.x, h0, l0); split_bf(v.y, h1, l1);
            split_bf(v.z, h2, l2); split_bf(v.w, h3, l3);
            uint2 hp; hp.x = (unsigned)h0 | ((unsigned)h1 << 16); hp.y = (unsigned)h2 | ((unsigned)h3 << 16);
            uint2 lp; lp.x = (unsigned)l0 | ((unsigned)l1 << 16); lp.y = (unsigned)l2 | ((unsigned)l3 << 16);
            *(uint2*)&ahi[row * 136 + 4 * kq] = hp;
            *(uint2*)&alo[row * 136 + 4 * kq] = lp;
        }
        __syncthreads();
#pragma unroll
        for (int c4 = 0; c4 < 4; ++c4) {
            const int k0 = c4 * 32;
            short8 bh[2], bl[2];
#pragma unroll
            for (int t = 0; t < 2; ++t) {
                const int g = ((2 * w + t) * 16 + l16) * 256 + half * 128 + k0 + quad * 8;
                bh[t] = ld_s8(&wTh[g]);
                bl[t] = ld_s8(&wTl[g]);
            }
#pragma unroll
            for (int mt = 0; mt < 4; ++mt) {
                const int base = (mt * 16 + l16) * 136 + k0 + quad * 8;
                const short8 ah = ld_s8(&ahi[base]);
                const short8 al = ld_s8(&alo[base]);
#pragma unroll
                for (int t = 0; t < 2; ++t) {
                    acc[mt][t] = __builtin_amdgcn_mfma_f32_16x16x32_bf16(ah, bh[t], acc[mt][t], 0, 0, 0);
                    acc[mt][t] = __builtin_amdgcn_mfma_f32_16x16x32_bf16(ah, bl[t], acc[mt][t], 0, 0, 0);
                    acc[mt][t] = __builtin_amdgcn_mfma_f32_16x16x32_bf16(al, bh[t], acc[mt][t], 0, 0, 0);
                }
            }
        }
    }
    node_epilogue_proj(acc, ahi, alo, bias, v1h, v1l, v2h, v2l, C, P1, P2, r0, M, w, quad, l16);
}

// ---- fused edge path (R7 config: 64-edge tiles, 256 threads) ----
__global__ __launch_bounds__(256) void edge_msg_mfma_kernel(
    const float* __restrict__ edge_feats,
    const int* __restrict__ perm, const int* __restrict__ ssrc, const int* __restrict__ sdst,
    const unsigned short* __restrict__ wehT_h, const unsigned short* __restrict__ wehT_l,
    const float* __restrict__ be,
    const unsigned short* __restrict__ wmT_h, const unsigned short* __restrict__ wmT_l,
    const float* __restrict__ bm,
    const float* __restrict__ Psrc, const float* __restrict__ Pdst,
    float* __restrict__ agg, int E)
{
    __shared__ __align__(16) char smem[45568];
    unsigned short* ahi = (unsigned short*)smem;            // [64][136]
    unsigned short* alo = (unsigned short*)(smem + 17408);
    unsigned short* efh = (unsigned short*)(smem + 34816);  // [64][40]
    unsigned short* efl = (unsigned short*)(smem + 39936);
    int* sdh = (int*)(smem + 45056);
    int* ssh = (int*)(smem + 45312);
    float* ms = (float*)smem;                               // [64][132] overlay

    const int tid = threadIdx.x;
    const int w = tid >> 6;
    const int l = tid & 63;
    const int quad = l >> 4;
    const int l16 = l & 15;
    const int p0 = blockIdx.x * 64;

    if (tid < 64) {
        const int p = p0 + tid;
        sdh[tid] = (p < E) ? sdst[p] : -1;
        ssh[tid] = (p < E) ? ssrc[p] : 0;
    }
    {
        const int row = tid >> 2, k16 = 16 + (tid & 3) * 4;
        *(ulong1*)&efh[row * 40 + k16] = ulong1{0};
        *(ulong1*)&efl[row * 40 + k16] = ulong1{0};
    }
    {
        const int row = tid >> 2, c4 = (tid & 3) * 4;
        const int p = p0 + row;
        float4 v = f4zero();
        if (p < E) {
            const int e = perm[p];
            v = *(const float4*)&edge_feats[(size_t)e * 16 + c4];
        }
        unsigned short h, lo;
        split_bf(v.x, h, lo); efh[row * 40 + c4 + 0] = h; efl[row * 40 + c4 + 0] = lo;
        split_bf(v.y, h, lo); efh[row * 40 + c4 + 1] = h; efl[row * 40 + c4 + 1] = lo;
        split_bf(v.z, h, lo); efh[row * 40 + c4 + 2] = h; efl[row * 40 + c4 + 2] = lo;
        split_bf(v.w, h, lo); efh[row * 40 + c4 + 3] = h; efl[row * 40 + c4 + 3] = lo;
    }
    __syncthreads();

    float4v acc[4][2];
#pragma unroll
    for (int mt = 0; mt < 4; ++mt)
#pragma unroll
        for (int t = 0; t < 2; ++t) acc[mt][t] = (float4v)0.f;

    // he phase: K=32 (zero-padded)
    {
        short8 bh[2], bl[2];
#pragma unroll
        for (int t = 0; t < 2; ++t) {
            const int g = ((2 * w + t) * 16 + l16) * 32 + quad * 8;
            bh[t] = ld_s8(&wehT_h[g]);
            bl[t] = ld_s8(&wehT_l[g]);
        }
#pragma unroll
        for (int mt = 0; mt < 4; ++mt) {
            const int base = (mt * 16 + l16) * 40 + quad * 8;
            const short8 ah = ld_s8(&efh[base]);
            const short8 al = ld_s8(&efl[base]);
#pragma unroll
            for (int t = 0; t < 2; ++t) {
                acc[mt][t] = __builtin_amdgcn_mfma_f32_16x16x32_bf16(ah, bh[t], acc[mt][t], 0, 0, 0);
                acc[mt][t] = __builtin_amdgcn_mfma_f32_16x16x32_bf16(ah, bl[t], acc[mt][t], 0, 0, 0);
                acc[mt][t] = __builtin_amdgcn_mfma_f32_16x16x32_bf16(al, bh[t], acc[mt][t], 0, 0, 0);
            }
        }
#pragma unroll
        for (int t = 0; t < 2; ++t) {
            const int col = (2 * w + t) * 16 + l16;
            const float bcol = be[col];
#pragma unroll
            for (int mt = 0; mt < 4; ++mt)
#pragma unroll
                for (int r = 0; r < 4; ++r) {
                    const int row = mt * 16 + quad * 4 + r;
                    const float v = fmaxf(acc[mt][t][r] + bcol, 0.f);
                    unsigned short h, lo;
                    split_bf(v, h, lo);
                    ahi[row * 136 + col] = h;
                    alo[row * 136 + col] = lo;
                }
        }
    }
    __syncthreads();

    // mid GEMM: K=128, B direct from global
#pragma unroll
    for (int mt = 0; mt < 4; ++mt)
#pragma unroll
        for (int t = 0; t < 2; ++t) acc[mt][t] = (float4v)0.f;

#pragma unroll
    for (int c = 0; c < 4; ++c) {
        const int k0 = c * 32;
        short8 bh[2], bl[2];
#pragma unroll
        for (int t = 0; t < 2; ++t) {
            const int g = ((2 * w + t) * 16 + l16) * 128 + k0 + quad * 8;
            bh[t] = ld_s8(&wmT_h[g]);
            bl[t] = ld_s8(&wmT_l[g]);
        }
#pragma unroll
        for (int mt = 0; mt < 4; ++mt) {
            const int base = (mt * 16 + l16) * 136 + k0 + quad * 8;
            const short8 ah = ld_s8(&ahi[base]);
            const short8 al = ld_s8(&alo[base]);
#pragma unroll
            for (int t = 0; t < 2; ++t) {
                acc[mt][t] = __builtin_amdgcn_mfma_f32_16x16x32_bf16(ah, bh[t], acc[mt][t], 0, 0, 0);
                acc[mt][t] = __builtin_amdgcn_mfma_f32_16x16x32_bf16(ah, bl[t], acc[mt][t], 0, 0, 0);
                acc[mt][t] = __builtin_amdgcn_mfma_f32_16x16x32_bf16(al, bh[t], acc[mt][t], 0, 0, 0);
            }
        }
    }
    __syncthreads();

    // spill to ms
#pragma unroll
    for (int mt = 0; mt < 4; ++mt)
#pragma unroll
        for (int t = 0; t < 2; ++t) {
            const int col = (2 * w + t) * 16 + l16;
#pragma unroll
            for (int r = 0; r < 4; ++r)
                ms[(mt * 16 + quad * 4 + r) * 132 + col] = acc[mt][t][r];
        }
    __syncthreads();

    // epilogue
    {
        const int tx = tid & 31, ty = tid >> 5;
        const float4 bm4 = *(const float4*)&bm[4 * tx];
#pragma unroll
        for (int i = 0; i < 8; ++i) {
            const int row = 8 * ty + i;
            const int p = p0 + row;
            if (p < E) {
                const int s = ssh[row];
                const int d = sdh[row];
                const float4 ps = *(const float4*)&Psrc[(size_t)s * 128 + 4 * tx];
                const float4 pd = *(const float4*)&Pdst[(size_t)d * 128 + 4 * tx];
                float4 m4 = *(const float4*)&ms[row * 132 + 4 * tx];
                m4.x = fmaxf(m4.x + bm4.x + ps.x + pd.x, 0.f);
                m4.y = fmaxf(m4.y + bm4.y + ps.y + pd.y, 0.f);
                m4.z = fmaxf(m4.z + bm4.z + ps.z + pd.z, 0.f);
                m4.w = fmaxf(m4.w + bm4.w + ps.w + pd.w, 0.f);
                *(float4*)&ms[row * 132 + 4 * tx] = m4;
            }
        }
    }
    __syncthreads();

    // run-length segmented reduction
    {
        const int j = tid & 127;
        const int base = (tid < 128) ? 0 : 32;
        float a = 0.f;
        for (int r = base; r < base + 32; ++r) {
            const int d = sdh[r];
            if (d < 0) break;
            a += ms[r * 132 + j];
            if (r == base + 31 || sdh[r + 1] != d) {
                atomicAdd(&agg[(size_t)d * 128 + j], a);
                a = 0.f;
            }
        }
    }
}

// ---- readout: one demand per wave ----
__global__ __launch_bounds__(256) void readout_kernel(
    const float* __restrict__ Qs, const float* __restrict__ Qd,
    const float* __restrict__ df, const int* __restrict__ dp,
    const float* __restrict__ Wd, const float* __restrict__ b1,
    const float* __restrict__ w2, const float* __restrict__ b2,
    float* __restrict__ out, int D)
{
    __shared__ float wd[8 * 128];
    const int tid = threadIdx.x;
    const int wv = tid >> 6;
    const int l = tid & 63;
    for (int idx = tid; idx < 8 * 128; idx += 256) wd[idx] = Wd[idx];
    __syncthreads();
    const float b1a = b1[l], b1b = b1[l + 64];
    const float w2a = w2[l], w2b = w2[l + 64];
    const float bb = b2[0];
    for (int d = blockIdx.x * 4 + wv; d < D; d += gridDim.x * 4) {
        const int s = dp[2 * d], t = dp[2 * d + 1];
        float a = b1a + Qs[(size_t)s * 128 + l] + Qd[(size_t)t * 128 + l];
        float b = b1b + Qs[(size_t)s * 128 + l + 64] + Qd[(size_t)t * 128 + l + 64];
#pragma unroll
        for (int k = 0; k < 8; ++k) {
            const float f = df[(size_t)d * 8 + k];
            a = fmaf(f, wd[k * 128 + l], a);
            b = fmaf(f, wd[k * 128 + l + 64], b);
        }
        float v = fmaxf(a, 0.f) * w2a + fmaxf(b, 0.f) * w2b;
        for (int o = 32; o > 0; o >>= 1) v += __shfl_down(v, o);
        if (l == 0) out[d] = 1.f / (1.f + __expf(-(v + bb)));
    }
}

extern "C" void kernel_launch(void* const* d_in, const int* in_sizes, int n_in,
                              void* d_out, int out_size, void* d_ws, size_t ws_size,
                              hipStream_t stream)
{
    const float* node_feats   = (const float*)d_in[0];
    const float* edge_feats   = (const float*)d_in[1];
    const float* demand_feats = (const float*)d_in[2];
    const int*   ei = (const int*)d_in[3];
    const int*   dp = (const int*)d_in[4];
    const float* W_node = (const float*)d_in[5];
    const float* b_node = (const float*)d_in[6];
    const float* W_edge = (const float*)d_in[7];
    const float* b_edge = (const float*)d_in[8];
    const float* Wm[2] = {(const float*)d_in[9],  (const float*)d_in[13]};
    const float* bm[2] = {(const float*)d_in[10], (const float*)d_in[14]};
    const float* Wu[2] = {(const float*)d_in[11], (const float*)d_in[15]};
    const float* bu[2] = {(const float*)d_in[12], (const float*)d_in[16]};
    const float* W_r1 = (const float*)d_in[17];
    const float* b_r1 = (const float*)d_in[18];
    const float* W_r2 = (const float*)d_in[19];
    const float* b_r2 = (const float*)d_in[20];
    float* out = (float*)d_out;

    const int NN = in_sizes[0] / 32;   // 20000
    const int NE = in_sizes[3] / 2;    // 640000
    const int ND = in_sizes[4] / 2;    // 100000

    float* B0 = (float*)d_ws;
    float* B1 = B0 + (size_t)NN * 128;
    float* B2 = B1 + (size_t)NN * 128;
    float* B3 = B2 + (size_t)NN * 128;
    int* cnt  = (int*)(B3 + (size_t)NN * 128);
    int* fill = cnt + NN;
    int* perm = fill + NN;
    int* ssrc = perm + NE;
    int* sdst = ssrc + NE;
    unsigned short* wehT_h = (unsigned short*)(sdst + NE);
    unsigned short* wehT_l = wehT_h + 128 * 32;
    unsigned short* wnT_h  = wehT_l + 128 * 32;
    unsigned short* wnT_l  = wnT_h + 128 * 32;
    unsigned short* spl8_h = wnT_l + 128 * 32;          // 8 x 16384
    unsigned short* spl8_l = spl8_h + 8 * 16384;
    unsigned short* wu_h   = spl8_l + 8 * 16384;        // 2 x 32768
    unsigned short* wu_l   = wu_h + 2 * 32768;

    // spl8 slots: 0=Wm0mid 1=Wm1mid 2=Wm0a 3=Wm0d 4=Wm1a 5=Wm1d 6=Wr1a 7=Wr1b
    unsigned short* wm0mid_h = spl8_h + 0 * 16384; unsigned short* wm0mid_l = spl8_l + 0 * 16384;
    unsigned short* wm1mid_h = spl8_h + 1 * 16384; unsigned short* wm1mid_l = spl8_l + 1 * 16384;
    unsigned short* wm0a_h   = spl8_h + 2 * 16384; unsigned short* wm0a_l   = spl8_l + 2 * 16384;
    unsigned short* wm0d_h   = spl8_h + 3 * 16384; unsigned short* wm0d_l   = spl8_l + 3 * 16384;
    unsigned short* wm1a_h   = spl8_h + 4 * 16384; unsigned short* wm1a_l   = spl8_l + 4 * 16384;
    unsigned short* wm1d_h   = spl8_h + 5 * 16384; unsigned short* wm1d_l   = spl8_l + 5 * 16384;
    unsigned short* wr1a_h   = spl8_h + 6 * 16384; unsigned short* wr1a_l   = spl8_l + 6 * 16384;
    unsigned short* wr1b_h   = spl8_h + 7 * 16384; unsigned short* wr1b_l   = spl8_l + 7 * 16384;
    unsigned short* wu0_h = wu_h + 0;      unsigned short* wu0_l = wu_l + 0;
    unsigned short* wu1_h = wu_h + 32768;  unsigned short* wu1_l = wu_l + 32768;

    const int nbN = (NN + 63) / 64;
    const int nbE = (NE + 63) / 64;

    // ---- weight prep ----
    tsplit_kernel<<<16, 256, 0, stream>>>(W_edge, 16, 128, 32, wehT_h, wehT_l);
    tsplit_kernel<<<16, 256, 0, stream>>>(W_node, 32, 128, 32, wnT_h, wnT_l);
    {
        SrcList8 s8;
        s8.p[0] = Wm[0] + 128 * 128; s8.p[1] = Wm[1] + 128 * 128;
        s8.p[2] = Wm[0];             s8.p[3] = Wm[0] + 256 * 128;
        s8.p[4] = Wm[1];             s8.p[5] = Wm[1] + 256 * 128;
        s8.p[6] = W_r1;              s8.p[7] = W_r1 + 128 * 128;
        tsplit8_kernel<<<512, 256, 0, stream>>>(s8, spl8_h, spl8_l);
    }
    {
        SrcList2 s2;
        s2.p[0] = Wu[0]; s2.p[1] = Wu[1];
        tsplit2_kernel<<<256, 256, 0, stream>>>(s2, wu_h, wu_l);
    }

    // ---- sort edges by dst ----
    hipMemsetAsync(cnt, 0, NN * sizeof(int), stream);
    hist_kernel<<<(NE + 255) / 256, 256, 0, stream>>>(ei, cnt, NE);
    scan_kernel<<<1, 256, 0, stream>>>(cnt, fill, NN);
    scatter_kernel<<<(NE + 255) / 256, 256, 0, stream>>>(ei, fill, perm, ssrc, sdst, NE);

    // ---- encode + layer-0 projections: h0 -> B0, Ps0 -> B1, Pd0 -> B2 ----
    encode_mfma_kernel<<<nbN, 256, 0, stream>>>(node_feats, wnT_h, wnT_l, b_node,
                                                wm0a_h, wm0a_l, wm0d_h, wm0d_l,
                                                B0, B1, B2, NN);
    // ---- layer 0 edge ----
    hipMemsetAsync(B3, 0, (size_t)NN * 128 * sizeof(float), stream);
    edge_msg_mfma_kernel<<<nbE, 256, 0, stream>>>(edge_feats, perm, ssrc, sdst,
                                                  wehT_h, wehT_l, b_edge,
                                                  wm0mid_h, wm0mid_l, bm[0], B1, B2, B3, NE);
    // ---- update 0 + layer-1 projections: h1 -> B0 (in place), Ps1 -> B1, Pd1 -> B2 ----
    update_mfma_kernel<<<nbN, 256, 0, stream>>>(B0, B3, wu0_h, wu0_l, bu[0],
                                                wm1a_h, wm1a_l, wm1d_h, wm1d_l,
                                                B0, B1, B2, NN);
    // ---- layer 1 edge ----
    hipMemsetAsync(B3, 0, (size_t)NN * 128 * sizeof(float), stream);
    edge_msg_mfma_kernel<<<nbE, 256, 0, stream>>>(edge_feats, perm, ssrc, sdst,
                                                  wehT_h, wehT_l, b_edge,
                                                  wm1mid_h, wm1mid_l, bm[1], B1, B2, B3, NE);
    // ---- update 1 + readout projections: h2 -> B0, Qs -> B1, Qd -> B2 ----
    update_mfma_kernel<<<nbN, 256, 0, stream>>>(B0, B3, wu1_h, wu1_l, bu[1],
                                                wr1a_h, wr1a_l, wr1b_h, wr1b_l,
                                                B0, B1, B2, NN);
    // ---- readout ----
    readout_kernel<<<2048, 256, 0, stream>>>(B1, B2, demand_feats, dp,
                                             W_r1 + 256 * 128, b_r1, W_r2, b_r2, out, ND);
}

// Round 11
// 655.104 us; speedup vs baseline: 1.2990x; 1.0489x over previous
//
#include <hip/hip_runtime.h>
#include <hip/hip_bf16.h>

using short8  = __attribute__((ext_vector_type(8))) short;
using float4v = __attribute__((ext_vector_type(4))) float;

__device__ __forceinline__ float4 f4zero() { return make_float4(0.f, 0.f, 0.f, 0.f); }

__device__ __forceinline__ float bfhi2f(unsigned short u) {
    return __uint_as_float(((unsigned int)u) << 16);
}
__device__ __forceinline__ unsigned short f2bf_rn(float x) {
    unsigned int u = __float_as_uint(x);
    u += 0x7FFFu + ((u >> 16) & 1u);
    return (unsigned short)(u >> 16);
}
__device__ __forceinline__ void split_bf(float v, unsigned short& h, unsigned short& l) {
    h = f2bf_rn(v);
    l = f2bf_rn(v - bfhi2f(h));
}
__device__ __forceinline__ short8 ld_s8(const unsigned short* p) {   // 16B-aligned
    return *(const short8*)p;
}

// ---------------- weight prep ----------------
// pair of small weights: W[K][128] -> [128][32] hi/lo, zero-padded; matrix m at offset m*4096
__global__ __launch_bounds__(256) void tsplit_pair_kernel(
    const float* __restrict__ W0, int K0, const float* __restrict__ W1, int K1,
    unsigned short* __restrict__ oh, unsigned short* __restrict__ ol)
{
    const int m = blockIdx.x >> 4;
    const int idx = (blockIdx.x & 15) * 256 + threadIdx.x;   // 0..4095
    const int n = idx >> 5, k = idx & 31;
    const float* W = m ? W1 : W0;
    const int K = m ? K1 : K0;
    const float v = (k < K) ? W[(size_t)k * 128 + n] : 0.f;
    unsigned short h, l;
    split_bf(v, h, l);
    oh[m * 4096 + idx] = h; ol[m * 4096 + idx] = l;
}

struct SrcList8 { const float* p[8]; };
__global__ __launch_bounds__(256) void tsplit8_kernel(
    SrcList8 src, unsigned short* __restrict__ dh, unsigned short* __restrict__ dl)
{
    const int m = blockIdx.x >> 6;
    const int idx = (blockIdx.x & 63) * 256 + threadIdx.x;  // 0..16383
    const int n = idx >> 7, k = idx & 127;
    const float v = src.p[m][(size_t)k * 128 + n];
    unsigned short h, l;
    split_bf(v, h, l);
    dh[m * 16384 + idx] = h; dl[m * 16384 + idx] = l;
}

struct SrcList2 { const float* p[2]; };
__global__ __launch_bounds__(256) void tsplit2_kernel(
    SrcList2 src, unsigned short* __restrict__ dh, unsigned short* __restrict__ dl)
{
    const int m = blockIdx.x >> 7;
    const int idx = (blockIdx.x & 127) * 256 + threadIdx.x; // 0..32767
    const int n = idx >> 8, k = idx & 255;
    const float v = src.p[m][(size_t)k * 128 + n];
    unsigned short h, l;
    split_bf(v, h, l);
    dh[m * 32768 + idx] = h; dl[m * 32768 + idx] = l;
}

// ---------------- sort pipeline ----------------
__global__ __launch_bounds__(256) void hist_kernel(
    const int* __restrict__ ei, int* __restrict__ cnt, int E)
{
    const int i = blockIdx.x * blockDim.x + threadIdx.x;
    if (i < E) atomicAdd(&cnt[ei[E + i]], 1);
}

__global__ __launch_bounds__(256) void scan_kernel(
    const int* __restrict__ cnt, int* __restrict__ fill, int n)
{
    __shared__ int part[256];
    const int tid = threadIdx.x;
    const int chunk = (n + 255) / 256;
    const int beg = tid * chunk;
    const int end = min(beg + chunk, n);
    int s = 0;
    for (int i = beg; i < end; ++i) s += cnt[i];
    part[tid] = s;
    __syncthreads();
    for (int off = 1; off < 256; off <<= 1) {
        const int v = (tid >= off) ? part[tid - off] : 0;
        __syncthreads();
        part[tid] += v;
        __syncthreads();
    }
    int prefix = (tid == 0) ? 0 : part[tid - 1];
    for (int i = beg; i < end; ++i) { fill[i] = prefix; prefix += cnt[i]; }
}

__global__ __launch_bounds__(256) void scatter_kernel(
    const int* __restrict__ ei, int* __restrict__ fill,
    int* __restrict__ perm, int* __restrict__ ssrc, int* __restrict__ sdst, int E)
{
    const int e = blockIdx.x * blockDim.x + threadIdx.x;
    if (e < E) {
        const int d = ei[E + e];
        const int pos = atomicAdd(&fill[d], 1);
        perm[pos] = e;
        ssrc[pos] = ei[e];
        sdst[pos] = d;
    }
}

// =====================================================================
// Fused node kernels (unchanged from R10)
// =====================================================================
__device__ __forceinline__ void node_epilogue_proj(
    float4v (&acc)[4][2], unsigned short* ahi, unsigned short* alo,
    const float* bias, const unsigned short* v1h, const unsigned short* v1l,
    const unsigned short* v2h, const unsigned short* v2l,
    float* C, float* P1, float* P2,
    int r0, int M, int w, int quad, int l16)
{
    __syncthreads();
#pragma unroll
    for (int t = 0; t < 2; ++t) {
        const int col = (2 * w + t) * 16 + l16;
        const float bcol = bias[col];
#pragma unroll
        for (int mt = 0; mt < 4; ++mt)
#pragma unroll
            for (int r = 0; r < 4; ++r) {
                const int row = mt * 16 + quad * 4 + r;
                const float c = fmaxf(acc[mt][t][r] + bcol, 0.f);
                if (r0 + row < M) C[(size_t)(r0 + row) * 128 + col] = c;
                unsigned short h, l;
                split_bf(c, h, l);
                ahi[row * 136 + col] = h;
                alo[row * 136 + col] = l;
            }
    }
    __syncthreads();
    const unsigned short* vh[2] = {v1h, v2h};
    const unsigned short* vl[2] = {v1l, v2l};
    float* P[2] = {P1, P2};
#pragma unroll
    for (int p = 0; p < 2; ++p) {
#pragma unroll
        for (int mt = 0; mt < 4; ++mt)
#pragma unroll
            for (int t = 0; t < 2; ++t) acc[mt][t] = (float4v)0.f;
#pragma unroll
        for (int c4 = 0; c4 < 4; ++c4) {
            const int k0 = c4 * 32;
            short8 bh[2], bl[2];
#pragma unroll
            for (int t = 0; t < 2; ++t) {
                const int g = ((2 * w + t) * 16 + l16) * 128 + k0 + quad * 8;
                bh[t] = ld_s8(&vh[p][g]);
                bl[t] = ld_s8(&vl[p][g]);
            }
#pragma unroll
            for (int mt = 0; mt < 4; ++mt) {
                const int base = (mt * 16 + l16) * 136 + k0 + quad * 8;
                const short8 ah = ld_s8(&ahi[base]);
                const short8 al = ld_s8(&alo[base]);
#pragma unroll
                for (int t = 0; t < 2; ++t) {
                    acc[mt][t] = __builtin_amdgcn_mfma_f32_16x16x32_bf16(ah, bh[t], acc[mt][t], 0, 0, 0);
                    acc[mt][t] = __builtin_amdgcn_mfma_f32_16x16x32_bf16(ah, bl[t], acc[mt][t], 0, 0, 0);
                    acc[mt][t] = __builtin_amdgcn_mfma_f32_16x16x32_bf16(al, bh[t], acc[mt][t], 0, 0, 0);
                }
            }
        }
#pragma unroll
        for (int t = 0; t < 2; ++t) {
            const int col = (2 * w + t) * 16 + l16;
#pragma unroll
            for (int mt = 0; mt < 4; ++mt)
#pragma unroll
                for (int r = 0; r < 4; ++r) {
                    const int row = mt * 16 + quad * 4 + r;
                    if (r0 + row < M) P[p][(size_t)(r0 + row) * 128 + col] = acc[mt][t][r];
                }
        }
    }
}

__global__ __launch_bounds__(256) void encode_mfma_kernel(
    const float* __restrict__ X,
    const unsigned short* __restrict__ wTh, const unsigned short* __restrict__ wTl,
    const float* __restrict__ bias,
    const unsigned short* __restrict__ v1h, const unsigned short* __restrict__ v1l,
    const unsigned short* __restrict__ v2h, const unsigned short* __restrict__ v2l,
    float* __restrict__ C, float* __restrict__ P1, float* __restrict__ P2, int M)
{
    __shared__ __align__(16) char smem[34816];
    unsigned short* ahi = (unsigned short*)smem;
    unsigned short* alo = (unsigned short*)(smem + 17408);
    const int tid = threadIdx.x;
    const int w = tid >> 6, l = tid & 63, quad = l >> 4, l16 = l & 15;
    const int r0 = blockIdx.x * 64;

#pragma unroll
    for (int rep = 0; rep < 2; ++rep) {
        const int fid = tid + rep * 256;
        const int row = fid >> 3, kq = fid & 7;
        float4 v = f4zero();
        if (r0 + row < M) v = *(const float4*)&X[(size_t)(r0 + row) * 32 + 4 * kq];
        unsigned short h0, l0, h1, l1, h2, l2, h3, l3;
        split_bf(v.x, h0, l0); split_bf(v.y, h1, l1);
        split_bf(v.z, h2, l2); split_bf(v.w, h3, l3);
        uint2 hp; hp.x = (unsigned)h0 | ((unsigned)h1 << 16); hp.y = (unsigned)h2 | ((unsigned)h3 << 16);
        uint2 lp; lp.x = (unsigned)l0 | ((unsigned)l1 << 16); lp.y = (unsigned)l2 | ((unsigned)l3 << 16);
        *(uint2*)&ahi[row * 136 + 4 * kq] = hp;
        *(uint2*)&alo[row * 136 + 4 * kq] = lp;
    }
    __syncthreads();

    float4v acc[4][2];
#pragma unroll
    for (int mt = 0; mt < 4; ++mt)
#pragma unroll
        for (int t = 0; t < 2; ++t) acc[mt][t] = (float4v)0.f;

    {
        short8 bh[2], bl[2];
#pragma unroll
        for (int t = 0; t < 2; ++t) {
            const int g = ((2 * w + t) * 16 + l16) * 32 + quad * 8;
            bh[t] = ld_s8(&wTh[g]);
            bl[t] = ld_s8(&wTl[g]);
        }
#pragma unroll
        for (int mt = 0; mt < 4; ++mt) {
            const int base = (mt * 16 + l16) * 136 + quad * 8;
            const short8 ah = ld_s8(&ahi[base]);
            const short8 al = ld_s8(&alo[base]);
#pragma unroll
            for (int t = 0; t < 2; ++t) {
                acc[mt][t] = __builtin_amdgcn_mfma_f32_16x16x32_bf16(ah, bh[t], acc[mt][t], 0, 0, 0);
                acc[mt][t] = __builtin_amdgcn_mfma_f32_16x16x32_bf16(ah, bl[t], acc[mt][t], 0, 0, 0);
                acc[mt][t] = __builtin_amdgcn_mfma_f32_16x16x32_bf16(al, bh[t], acc[mt][t], 0, 0, 0);
            }
        }
    }
    node_epilogue_proj(acc, ahi, alo, bias, v1h, v1l, v2h, v2l, C, P1, P2, r0, M, w, quad, l16);
}

__global__ __launch_bounds__(256) void update_mfma_kernel(
    const float* __restrict__ A1, const float* __restrict__ A2,
    const unsigned short* __restrict__ wTh, const unsigned short* __restrict__ wTl,
    const float* __restrict__ bias,
    const unsigned short* __restrict__ v1h, const unsigned short* __restrict__ v1l,
    const unsigned short* __restrict__ v2h, const unsigned short* __restrict__ v2l,
    float* __restrict__ C, float* __restrict__ P1, float* __restrict__ P2, int M)
{
    __shared__ __align__(16) char smem[34816];
    unsigned short* ahi = (unsigned short*)smem;
    unsigned short* alo = (unsigned short*)(smem + 17408);
    const int tid = threadIdx.x;
    const int w = tid >> 6, l = tid & 63, quad = l >> 4, l16 = l & 15;
    const int r0 = blockIdx.x * 64;

    float4v acc[4][2];
#pragma unroll
    for (int mt = 0; mt < 4; ++mt)
#pragma unroll
        for (int t = 0; t < 2; ++t) acc[mt][t] = (float4v)0.f;

    for (int half = 0; half < 2; ++half) {
        const float* A = half ? A2 : A1;
        if (half) __syncthreads();
#pragma unroll
        for (int rep = 0; rep < 8; ++rep) {
            const int fid = tid + rep * 256;
            const int row = fid >> 5, kq = fid & 31;
            float4 v = f4zero();
            if (r0 + row < M) v = *(const float4*)&A[(size_t)(r0 + row) * 128 + 4 * kq];
            unsigned short h0, l0, h1, l1, h2, l2, h3, l3;
            split_bf(v.x, h0, l0); split_bf(v.y, h1, l1);
            split_bf(v.z, h2, l2); split_bf(v.w, h3, l3);
            uint2 hp; hp.x = (unsigned)h0 | ((unsigned)h1 << 16); hp.y = (unsigned)h2 | ((unsigned)h3 << 16);
            uint2 lp; lp.x = (unsigned)l0 | ((unsigned)l1 << 16); lp.y = (unsigned)l2 | ((unsigned)l3 << 16);
            *(uint2*)&ahi[row * 136 + 4 * kq] = hp;
            *(uint2*)&alo[row * 136 + 4 * kq] = lp;
        }
        __syncthreads();
#pragma unroll
        for (int c4 = 0; c4 < 4; ++c4) {
            const int k0 = c4 * 32;
            short8 bh[2], bl[2];
#pragma unroll
            for (int t = 0; t < 2; ++t) {
                const int g = ((2 * w + t) * 16 + l16) * 256 + half * 128 + k0 + quad * 8;
                bh[t] = ld_s8(&wTh[g]);
                bl[t] = ld_s8(&wTl[g]);
            }
#pragma unroll
            for (int mt = 0; mt < 4; ++mt) {
                const int base = (mt * 16 + l16) * 136 + k0 + quad * 8;
                const short8 ah = ld_s8(&ahi[base]);
                const short8 al = ld_s8(&alo[base]);
#pragma unroll
                for (int t = 0; t < 2; ++t) {
                    acc[mt][t] = __builtin_amdgcn_mfma_f32_16x16x32_bf16(ah, bh[t], acc[mt][t], 0, 0, 0);
                    acc[mt][t] = __builtin_amdgcn_mfma_f32_16x16x32_bf16(ah, bl[t], acc[mt][t], 0, 0, 0);
                    acc[mt][t] = __builtin_amdgcn_mfma_f32_16x16x32_bf16(al, bh[t], acc[mt][t], 0, 0, 0);
                }
            }
        }
    }
    node_epilogue_proj(acc, ahi, alo, bias, v1h, v1l, v2h, v2l, C, P1, P2, r0, M, w, quad, l16);
}

// ---- fused edge path: 64-edge tiles, ef A-frags direct from global (no ef LDS) ----
// LDS 35584 B -> 4 blocks/CU.
__global__ __launch_bounds__(256, 4) void edge_msg_mfma_kernel(
    const float* __restrict__ edge_feats,
    const int* __restrict__ perm, const int* __restrict__ ssrc, const int* __restrict__ sdst,
    const unsigned short* __restrict__ wehT_h, const unsigned short* __restrict__ wehT_l,
    const float* __restrict__ be,
    const unsigned short* __restrict__ wmT_h, const unsigned short* __restrict__ wmT_l,
    const float* __restrict__ bm,
    const float* __restrict__ Psrc, const float* __restrict__ Pdst,
    float* __restrict__ agg, int E)
{
    __shared__ __align__(16) char smem[35584];
    unsigned short* ahi = (unsigned short*)smem;            // [64][136]
    unsigned short* alo = (unsigned short*)(smem + 17408);  // [64][136]
    int* sdh = (int*)(smem + 34816);
    int* ssh = (int*)(smem + 35072);
    int* peh = (int*)(smem + 35328);
    float* ms = (float*)smem;                               // [64][132] overlay

    const int tid = threadIdx.x;
    const int w = tid >> 6;
    const int l = tid & 63;
    const int quad = l >> 4;
    const int l16 = l & 15;
    const int p0 = blockIdx.x * 64;

    if (tid < 64) {
        const int p = p0 + tid;
        sdh[tid] = (p < E) ? sdst[p] : -1;
        ssh[tid] = (p < E) ? ssrc[p] : 0;
        peh[tid] = (p < E) ? perm[p] : 0;
    }
    __syncthreads();

    float4v acc[4][2];
#pragma unroll
    for (int mt = 0; mt < 4; ++mt)
#pragma unroll
        for (int t = 0; t < 2; ++t) acc[mt][t] = (float4v)0.f;

    // ---- he phase: per-lane A-frags from global (quads 2,3 = K-pad zeros) ----
    {
        short8 bh[2], bl[2];
#pragma unroll
        for (int t = 0; t < 2; ++t) {
            const int g = ((2 * w + t) * 16 + l16) * 32 + quad * 8;
            bh[t] = ld_s8(&wehT_h[g]);
            bl[t] = ld_s8(&wehT_l[g]);
        }
        const short8 zf = {0, 0, 0, 0, 0, 0, 0, 0};
#pragma unroll
        for (int mt = 0; mt < 4; ++mt) {
            short8 ah = zf, al = zf;
            if (quad < 2) {
                const int row = mt * 16 + l16;
                const int p = p0 + row;
                if (p < E) {
                    const int e = peh[row];
                    const float4 v0 = *(const float4*)&edge_feats[(size_t)e * 16 + quad * 8];
                    const float4 v1 = *(const float4*)&edge_feats[(size_t)e * 16 + quad * 8 + 4];
                    unsigned short h, lo;
                    split_bf(v0.x, h, lo); ah[0] = (short)h; al[0] = (short)lo;
                    split_bf(v0.y, h, lo); ah[1] = (short)h; al[1] = (short)lo;
                    split_bf(v0.z, h, lo); ah[2] = (short)h; al[2] = (short)lo;
                    split_bf(v0.w, h, lo); ah[3] = (short)h; al[3] = (short)lo;
                    split_bf(v1.x, h, lo); ah[4] = (short)h; al[4] = (short)lo;
                    split_bf(v1.y, h, lo); ah[5] = (short)h; al[5] = (short)lo;
                    split_bf(v1.z, h, lo); ah[6] = (short)h; al[6] = (short)lo;
                    split_bf(v1.w, h, lo); ah[7] = (short)h; al[7] = (short)lo;
                }
            }
#pragma unroll
            for (int t = 0; t < 2; ++t) {
                acc[mt][t] = __builtin_amdgcn_mfma_f32_16x16x32_bf16(ah, bh[t], acc[mt][t], 0, 0, 0);
                acc[mt][t] = __builtin_amdgcn_mfma_f32_16x16x32_bf16(ah, bl[t], acc[mt][t], 0, 0, 0);
                acc[mt][t] = __builtin_amdgcn_mfma_f32_16x16x32_bf16(al, bh[t], acc[mt][t], 0, 0, 0);
            }
        }
        // bias + relu + split -> ahi/alo
#pragma unroll
        for (int t = 0; t < 2; ++t) {
            const int col = (2 * w + t) * 16 + l16;
            const float bcol = be[col];
#pragma unroll
            for (int mt = 0; mt < 4; ++mt)
#pragma unroll
                for (int r = 0; r < 4; ++r) {
                    const int row = mt * 16 + quad * 4 + r;
                    const float v = fmaxf(acc[mt][t][r] + bcol, 0.f);
                    unsigned short h, lo;
                    split_bf(v, h, lo);
                    ahi[row * 136 + col] = h;
                    alo[row * 136 + col] = lo;
                }
        }
    }
    __syncthreads();

    // ---- mid GEMM: K=128, B direct from global ----
#pragma unroll
    for (int mt = 0; mt < 4; ++mt)
#pragma unroll
        for (int t = 0; t < 2; ++t) acc[mt][t] = (float4v)0.f;

#pragma unroll
    for (int c = 0; c < 4; ++c) {
        const int k0 = c * 32;
        short8 bh[2], bl[2];
#pragma unroll
        for (int t = 0; t < 2; ++t) {
            const int g = ((2 * w + t) * 16 + l16) * 128 + k0 + quad * 8;
            bh[t] = ld_s8(&wmT_h[g]);
            bl[t] = ld_s8(&wmT_l[g]);
        }
#pragma unroll
        for (int mt = 0; mt < 4; ++mt) {
            const int base = (mt * 16 + l16) * 136 + k0 + quad * 8;
            const short8 ah = ld_s8(&ahi[base]);
            const short8 al = ld_s8(&alo[base]);
#pragma unroll
            for (int t = 0; t < 2; ++t) {
                acc[mt][t] = __builtin_amdgcn_mfma_f32_16x16x32_bf16(ah, bh[t], acc[mt][t], 0, 0, 0);
                acc[mt][t] = __builtin_amdgcn_mfma_f32_16x16x32_bf16(ah, bl[t], acc[mt][t], 0, 0, 0);
                acc[mt][t] = __builtin_amdgcn_mfma_f32_16x16x32_bf16(al, bh[t], acc[mt][t], 0, 0, 0);
            }
        }
    }
    __syncthreads();   // ahi/alo reads done; safe to overlay ms

    // ---- spill to ms ----
#pragma unroll
    for (int mt = 0; mt < 4; ++mt)
#pragma unroll
        for (int t = 0; t < 2; ++t) {
            const int col = (2 * w + t) * 16 + l16;
#pragma unroll
            for (int r = 0; r < 4; ++r)
                ms[(mt * 16 + quad * 4 + r) * 132 + col] = acc[mt][t][r];
        }
    __syncthreads();

    // ---- epilogue: + bm + Ps[src] + Pd[dst], relu ----
    {
        const int tx = tid & 31, ty = tid >> 5;
        const float4 bm4 = *(const float4*)&bm[4 * tx];
#pragma unroll
        for (int i = 0; i < 8; ++i) {
            const int row = 8 * ty + i;
            const int p = p0 + row;
            if (p < E) {
                const int s = ssh[row];
                const int d = sdh[row];
                const float4 ps = *(const float4*)&Psrc[(size_t)s * 128 + 4 * tx];
                const float4 pd = *(const float4*)&Pdst[(size_t)d * 128 + 4 * tx];
                float4 m4 = *(const float4*)&ms[row * 132 + 4 * tx];
                m4.x = fmaxf(m4.x + bm4.x + ps.x + pd.x, 0.f);
                m4.y = fmaxf(m4.y + bm4.y + ps.y + pd.y, 0.f);
                m4.z = fmaxf(m4.z + bm4.z + ps.z + pd.z, 0.f);
                m4.w = fmaxf(m4.w + bm4.w + ps.w + pd.w, 0.f);
                *(float4*)&ms[row * 132 + 4 * tx] = m4;
            }
        }
    }
    __syncthreads();

    // ---- run-length segmented reduction ----
    {
        const int j = tid & 127;
        const int base = (tid < 128) ? 0 : 32;
        float a = 0.f;
        for (int r = base; r < base + 32; ++r) {
            const int d = sdh[r];
            if (d < 0) break;
            a += ms[r * 132 + j];
            if (r == base + 31 || sdh[r + 1] != d) {
                atomicAdd(&agg[(size_t)d * 128 + j], a);
                a = 0.f;
            }
        }
    }
}

// ---- readout: one demand per wave ----
__global__ __launch_bounds__(256) void readout_kernel(
    const float* __restrict__ Qs, const float* __restrict__ Qd,
    const float* __restrict__ df, const int* __restrict__ dp,
    const float* __restrict__ Wd, const float* __restrict__ b1,
    const float* __restrict__ w2, const float* __restrict__ b2,
    float* __restrict__ out, int D)
{
    __shared__ float wd[8 * 128];
    const int tid = threadIdx.x;
    const int wv = tid >> 6;
    const int l = tid & 63;
    for (int idx = tid; idx < 8 * 128; idx += 256) wd[idx] = Wd[idx];
    __syncthreads();
    const float b1a = b1[l], b1b = b1[l + 64];
    const float w2a = w2[l], w2b = w2[l + 64];
    const float bb = b2[0];
    for (int d = blockIdx.x * 4 + wv; d < D; d += gridDim.x * 4) {
        const int s = dp[2 * d], t = dp[2 * d + 1];
        float a = b1a + Qs[(size_t)s * 128 + l] + Qd[(size_t)t * 128 + l];
        float b = b1b + Qs[(size_t)s * 128 + l + 64] + Qd[(size_t)t * 128 + l + 64];
#pragma unroll
        for (int k = 0; k < 8; ++k) {
            const float f = df[(size_t)d * 8 + k];
            a = fmaf(f, wd[k * 128 + l], a);
            b = fmaf(f, wd[k * 128 + l + 64], b);
        }
        float v = fmaxf(a, 0.f) * w2a + fmaxf(b, 0.f) * w2b;
        for (int o = 32; o > 0; o >>= 1) v += __shfl_down(v, o);
        if (l == 0) out[d] = 1.f / (1.f + __expf(-(v + bb)));
    }
}

extern "C" void kernel_launch(void* const* d_in, const int* in_sizes, int n_in,
                              void* d_out, int out_size, void* d_ws, size_t ws_size,
                              hipStream_t stream)
{
    const float* node_feats   = (const float*)d_in[0];
    const float* edge_feats   = (const float*)d_in[1];
    const float* demand_feats = (const float*)d_in[2];
    const int*   ei = (const int*)d_in[3];
    const int*   dp = (const int*)d_in[4];
    const float* W_node = (const float*)d_in[5];
    const float* b_node = (const float*)d_in[6];
    const float* W_edge = (const float*)d_in[7];
    const float* b_edge = (const float*)d_in[8];
    const float* Wm[2] = {(const float*)d_in[9],  (const float*)d_in[13]};
    const float* bm[2] = {(const float*)d_in[10], (const float*)d_in[14]};
    const float* Wu[2] = {(const float*)d_in[11], (const float*)d_in[15]};
    const float* bu[2] = {(const float*)d_in[12], (const float*)d_in[16]};
    const float* W_r1 = (const float*)d_in[17];
    const float* b_r1 = (const float*)d_in[18];
    const float* W_r2 = (const float*)d_in[19];
    const float* b_r2 = (const float*)d_in[20];
    float* out = (float*)d_out;

    const int NN = in_sizes[0] / 32;   // 20000
    const int NE = in_sizes[3] / 2;    // 640000
    const int ND = in_sizes[4] / 2;    // 100000

    float* B0 = (float*)d_ws;
    float* B1 = B0 + (size_t)NN * 128;
    float* B2 = B1 + (size_t)NN * 128;
    float* B3 = B2 + (size_t)NN * 128;
    int* cnt  = (int*)(B3 + (size_t)NN * 128);
    int* fill = cnt + NN;
    int* perm = fill + NN;
    int* ssrc = perm + NE;
    int* sdst = ssrc + NE;
    // small-weight pair: [wehT | wnT] hi then lo (2 x 4096 each)
    unsigned short* wsm_h = (unsigned short*)(sdst + NE);
    unsigned short* wsm_l = wsm_h + 2 * 4096;
    unsigned short* wehT_h = wsm_h;          unsigned short* wehT_l = wsm_l;
    unsigned short* wnT_h  = wsm_h + 4096;   unsigned short* wnT_l  = wsm_l + 4096;
    unsigned short* spl8_h = wsm_l + 2 * 4096;          // 8 x 16384
    unsigned short* spl8_l = spl8_h + 8 * 16384;
    unsigned short* wu_h   = spl8_l + 8 * 16384;        // 2 x 32768
    unsigned short* wu_l   = wu_h + 2 * 32768;

    unsigned short* wm0mid_h = spl8_h + 0 * 16384; unsigned short* wm0mid_l = spl8_l + 0 * 16384;
    unsigned short* wm1mid_h = spl8_h + 1 * 16384; unsigned short* wm1mid_l = spl8_l + 1 * 16384;
    unsigned short* wm0a_h   = spl8_h + 2 * 16384; unsigned short* wm0a_l   = spl8_l + 2 * 16384;
    unsigned short* wm0d_h   = spl8_h + 3 * 16384; unsigned short* wm0d_l   = spl8_l + 3 * 16384;
    unsigned short* wm1a_h   = spl8_h + 4 * 16384; unsigned short* wm1a_l   = spl8_l + 4 * 16384;
    unsigned short* wm1d_h   = spl8_h + 5 * 16384; unsigned short* wm1d_l   = spl8_l + 5 * 16384;
    unsigned short* wr1a_h   = spl8_h + 6 * 16384; unsigned short* wr1a_l   = spl8_l + 6 * 16384;
    unsigned short* wr1b_h   = spl8_h + 7 * 16384; unsigned short* wr1b_l   = spl8_l + 7 * 16384;
    unsigned short* wu0_h = wu_h + 0;      unsigned short* wu0_l = wu_l + 0;
    unsigned short* wu1_h = wu_h + 32768;  unsigned short* wu1_l = wu_l + 32768;

    const int nbN = (NN + 63) / 64;
    const int nbE = (NE + 63) / 64;

    // ---- weight prep ----
    tsplit_pair_kernel<<<32, 256, 0, stream>>>(W_edge, 16, W_node, 32, wsm_h, wsm_l);
    {
        SrcList8 s8;
        s8.p[0] = Wm[0] + 128 * 128; s8.p[1] = Wm[1] + 128 * 128;
        s8.p[2] = Wm[0];             s8.p[3] = Wm[0] + 256 * 128;
        s8.p[4] = Wm[1];             s8.p[5] = Wm[1] + 256 * 128;
        s8.p[6] = W_r1;              s8.p[7] = W_r1 + 128 * 128;
        tsplit8_kernel<<<512, 256, 0, stream>>>(s8, spl8_h, spl8_l);
    }
    {
        SrcList2 s2;
        s2.p[0] = Wu[0]; s2.p[1] = Wu[1];
        tsplit2_kernel<<<256, 256, 0, stream>>>(s2, wu_h, wu_l);
    }

    // ---- sort edges by dst ----
    hipMemsetAsync(cnt, 0, NN * sizeof(int), stream);
    hist_kernel<<<(NE + 255) / 256, 256, 0, stream>>>(ei, cnt, NE);
    scan_kernel<<<1, 256, 0, stream>>>(cnt, fill, NN);
    scatter_kernel<<<(NE + 255) / 256, 256, 0, stream>>>(ei, fill, perm, ssrc, sdst, NE);

    // ---- encode + layer-0 projections ----
    encode_mfma_kernel<<<nbN, 256, 0, stream>>>(node_feats, wnT_h, wnT_l, b_node,
                                                wm0a_h, wm0a_l, wm0d_h, wm0d_l,
                                                B0, B1, B2, NN);
    // ---- layer 0 edge ----
    hipMemsetAsync(B3, 0, (size_t)NN * 128 * sizeof(float), stream);
    edge_msg_mfma_kernel<<<nbE, 256, 0, stream>>>(edge_feats, perm, ssrc, sdst,
                                                  wehT_h, wehT_l, b_edge,
                                                  wm0mid_h, wm0mid_l, bm[0], B1, B2, B3, NE);
    // ---- update 0 + layer-1 projections ----
    update_mfma_kernel<<<nbN, 256, 0, stream>>>(B0, B3, wu0_h, wu0_l, bu[0],
                                                wm1a_h, wm1a_l, wm1d_h, wm1d_l,
                                                B0, B1, B2, NN);
    // ---- layer 1 edge ----
    hipMemsetAsync(B3, 0, (size_t)NN * 128 * sizeof(float), stream);
    edge_msg_mfma_kernel<<<nbE, 256, 0, stream>>>(edge_feats, perm, ssrc, sdst,
                                                  wehT_h, wehT_l, b_edge,
                                                  wm1mid_h, wm1mid_l, bm[1], B1, B2, B3, NE);
    // ---- update 1 + readout projections ----
    update_mfma_kernel<<<nbN, 256, 0, stream>>>(B0, B3, wu1_h, wu1_l, bu[1],
                                                wr1a_h, wr1a_l, wr1b_h, wr1b_l,
                                                B0, B1, B2, NN);
    // ---- readout ----
    readout_kernel<<<2048, 256, 0, stream>>>(B1, B2, demand_feats, dp,
                                             W_r1 + 256 * 128, b_r1, W_r2, b_r2, out, ND);
}